// Round 11
// baseline (299.036 us; speedup 1.0000x reference)
//
#include <hip/hip_runtime.h>
#include <hip/hip_cooperative_groups.h>

namespace cg = cooperative_groups;

#define DIM 32
#define NPB 128            // nodes per bucket (shift 7)
#define NPB_SHIFT 7
#define NPB_MASK 127
#define MAXB 1024          // max buckets (LDS arrays)
#define CAP 4096           // edges sorted per pass in LDS
#define FIT 4              // fused chunk cache depth: chunk <= FIT*2048
#define PCHUNK 8192        // fallback hist/partition chunk
#define MAXBLK 256         // fallback colscan column length

__device__ inline void f4add(float4& a, float4 v) {
    a.x += v.x; a.y += v.y; a.z += v.z; a.w += v.w;
}

// Sum x4 rows listed in LDS `sorted[s0..s0+cnt)`; 8 independent gathers in flight.
__device__ inline void accum_node(const float4* __restrict__ x4,
                                  const int* sorted, int s0, int cnt, int q,
                                  float4& accA, float4& accB) {
    int k = 0;
    for (; k + 7 < cnt; k += 8) {
        int i0 = sorted[s0 + k],     i1 = sorted[s0 + k + 1];
        int i2 = sorted[s0 + k + 2], i3 = sorted[s0 + k + 3];
        int i4 = sorted[s0 + k + 4], i5 = sorted[s0 + k + 5];
        int i6 = sorted[s0 + k + 6], i7 = sorted[s0 + k + 7];
        float4 v0 = x4[i0 * 8 + q], v1 = x4[i1 * 8 + q];
        float4 v2 = x4[i2 * 8 + q], v3 = x4[i3 * 8 + q];
        float4 v4 = x4[i4 * 8 + q], v5 = x4[i5 * 8 + q];
        float4 v6 = x4[i6 * 8 + q], v7 = x4[i7 * 8 + q];
        f4add(accA, v0); f4add(accB, v1); f4add(accA, v2); f4add(accB, v3);
        f4add(accA, v4); f4add(accB, v5); f4add(accA, v6); f4add(accB, v7);
    }
    for (; k + 3 < cnt; k += 4) {
        int i0 = sorted[s0 + k],     i1 = sorted[s0 + k + 1];
        int i2 = sorted[s0 + k + 2], i3 = sorted[s0 + k + 3];
        float4 v0 = x4[i0 * 8 + q], v1 = x4[i1 * 8 + q];
        float4 v2 = x4[i2 * 8 + q], v3 = x4[i3 * 8 + q];
        f4add(accA, v0); f4add(accB, v1); f4add(accA, v2); f4add(accB, v3);
    }
    for (; k < cnt; ++k) f4add(accA, x4[sorted[s0 + k] * 8 + q]);
}

// ============ fused cooperative pipeline: hist -> scan -> partition -> agg ===

__global__ void __launch_bounds__(512)
fused_kernel(const float4* __restrict__ x4, const int* __restrict__ src,
             const int* __restrict__ dst, int* __restrict__ H,
             int* __restrict__ colsum, int* __restrict__ goff,
             int* __restrict__ packed, float4* __restrict__ out4,
             int n_nodes, int n_edges, int nbuckets, int chunk) {
    cg::grid_group gg = cg::this_grid();
    __shared__ int lh[MAXB];
    __shared__ int sh[512];
    __shared__ int lbase[MAXB];
    __shared__ int lrank[MAXB];
    __shared__ int shist[NPB];
    __shared__ int soff[NPB];
    __shared__ int scur[NPB];
    __shared__ int sorted[CAP];

    const int t   = threadIdx.x;
    const int blk = blockIdx.x;
    const int G   = gridDim.x;

    // ---- phase 1: per-chunk bucket histogram (dst cached in registers) ----
    for (int j = t; j < nbuckets; j += 512) lh[j] = 0;
    __syncthreads();
    const int c0 = blk * chunk;
    const int c1 = min(c0 + chunk, n_edges);
    int4 dc[FIT];
    int  nv[FIT];
#pragma unroll
    for (int g = 0; g < FIT; ++g) {
        int i = c0 + g * 2048 + t * 4;
        int4 d = make_int4(0, 0, 0, 0);
        int n = 0;
        if (i + 3 < c1) { d = *(const int4*)(dst + i); n = 4; }
        else if (i < c1) {
            n = c1 - i;
            int* dp = (int*)&d;
            for (int k = 0; k < n; ++k) dp[k] = dst[i + k];
        }
        dc[g] = d; nv[g] = n;
        int* dp = (int*)&d;
        for (int k = 0; k < n; ++k) atomicAdd(&lh[dp[k] >> NPB_SHIFT], 1);
    }
    __syncthreads();
    {
        int* row = H + (size_t)blk * nbuckets;
        for (int j = t; j < nbuckets; j += 512) row[j] = lh[j];
    }
    gg.sync();

    // ---- phase 2a: exclusive scan down each H column (2 elems/thread) ----
    for (int j = blk; j < nbuckets; j += G) {
        int i0 = 2 * t, i1 = 2 * t + 1;
        int v0 = (i0 < G) ? H[(size_t)i0 * nbuckets + j] : 0;
        int v1 = (i1 < G) ? H[(size_t)i1 * nbuckets + j] : 0;
        int pair = v0 + v1;
        sh[t] = pair;
        __syncthreads();
        for (int off = 1; off < 512; off <<= 1) {
            int u = (t >= off) ? sh[t - off] : 0;
            __syncthreads();
            sh[t] += u;
            __syncthreads();
        }
        int excl = sh[t] - pair;
        if (i0 < G) H[(size_t)i0 * nbuckets + j] = excl;
        if (i1 < G) H[(size_t)i1 * nbuckets + j] = excl + v0;
        if (t == 511) colsum[j] = sh[511];
        __syncthreads();
    }
    gg.sync();

    // ---- phase 2b: block 0 exclusive-scans colsum -> goff ----
    if (blk == 0) {
        int i0 = 2 * t, i1 = 2 * t + 1;
        int v0 = (i0 < nbuckets) ? colsum[i0] : 0;
        int v1 = (i1 < nbuckets) ? colsum[i1] : 0;
        int pair = v0 + v1;
        sh[t] = pair;
        __syncthreads();
        for (int off = 1; off < 512; off <<= 1) {
            int u = (t >= off) ? sh[t - off] : 0;
            __syncthreads();
            sh[t] += u;
            __syncthreads();
        }
        int excl = sh[t] - pair;
        if (i0 < nbuckets) goff[i0] = excl;
        if (i1 < nbuckets) goff[i1] = excl + v0;
    }
    gg.sync();

    // ---- phase 3: partition into packed (dst from register cache) ----
    {
        const int* row = H + (size_t)blk * nbuckets;
        for (int j = t; j < nbuckets; j += 512) {
            lbase[j] = goff[j] + row[j];
            lrank[j] = 0;
        }
    }
    __syncthreads();
#pragma unroll
    for (int g = 0; g < FIT; ++g) {
        int n = nv[g];
        if (n == 0) continue;
        int i = c0 + g * 2048 + t * 4;
        int4 s = make_int4(0, 0, 0, 0);
        if (n == 4) s = *(const int4*)(src + i);
        else { int* sp = (int*)&s; for (int k = 0; k < n; ++k) sp[k] = src[i + k]; }
        int* dp = (int*)&dc[g];
        int* sp = (int*)&s;
        for (int k = 0; k < n; ++k) {
            int d = dp[k], b = d >> NPB_SHIFT;
            int r = atomicAdd(&lrank[b], 1);
            packed[lbase[b] + r] = (sp[k] << NPB_SHIFT) | (d & NPB_MASK);
        }
    }
    gg.sync();

    // ---- phase 4: per-bucket LDS counting sort + atomic-free aggregation ----
    const int node = t >> 3;
    const int q    = t & 7;
    for (int b = blk; b < nbuckets; b += G) {
        int seg_start = goff[b];
        int seg_end   = (b + 1 < nbuckets) ? goff[b + 1] : n_edges;
        float4 a0A = {0,0,0,0}, a0B = {0,0,0,0};
        float4 a1A = {0,0,0,0}, a1B = {0,0,0,0};
        int deg0 = 0, deg1 = 0;
        __syncthreads();                      // smem handoff between buckets
        for (int pos = seg_start; pos < seg_end; pos += CAP) {
            int ch = min(CAP, seg_end - pos);
            for (int i = t; i < NPB; i += 512) shist[i] = 0;
            __syncthreads();
            int cc[8];
#pragma unroll
            for (int j = 0; j < 8; ++j) {
                int i = t + j * 512;
                if (i < ch) {
                    int p = packed[pos + i];
                    cc[j] = p;
                    atomicAdd(&shist[p & NPB_MASK], 1);
                }
            }
            __syncthreads();
            // barrier-free exclusive scan of 128 counts by wave 0
            if (t < 64) {
                int a  = shist[2 * t];
                int b2 = shist[2 * t + 1];
                int v = a + b2;
                for (int off = 1; off < 64; off <<= 1) {
                    int u = __shfl_up(v, off, 64);
                    if (t >= off) v += u;
                }
                int excl = v - (a + b2);
                soff[2 * t]     = excl;  soff[2 * t + 1] = excl + a;
                scur[2 * t]     = excl;  scur[2 * t + 1] = excl + a;
            }
            __syncthreads();
#pragma unroll
            for (int j = 0; j < 8; ++j) {
                int i = t + j * 512;
                if (i < ch) {
                    int p = cc[j];
                    int r = atomicAdd(&scur[p & NPB_MASK], 1);
                    sorted[r] = p >> NPB_SHIFT;
                }
            }
            __syncthreads();
            {
                int cnt0 = shist[node];
                accum_node(x4, sorted, soff[node], cnt0, q, a0A, a0B);
                deg0 += cnt0;
                int cnt1 = shist[node + 64];
                accum_node(x4, sorted, soff[node + 64], cnt1, q, a1A, a1B);
                deg1 += cnt1;
            }
            __syncthreads();
        }
        int n0 = b << NPB_SHIFT;
        int g0 = n0 + node;
        if (g0 < n_nodes) {
            float inv = 1.0f / (float)max(deg0, 1);
            float4 r;
            r.x = (a0A.x + a0B.x) * inv; r.y = (a0A.y + a0B.y) * inv;
            r.z = (a0A.z + a0B.z) * inv; r.w = (a0A.w + a0B.w) * inv;
            out4[g0 * 8 + q] = r;
        }
        int g1 = n0 + 64 + node;
        if (g1 < n_nodes) {
            float inv = 1.0f / (float)max(deg1, 1);
            float4 r;
            r.x = (a1A.x + a1B.x) * inv; r.y = (a1A.y + a1B.y) * inv;
            r.z = (a1A.z + a1B.z) * inv; r.w = (a1A.w + a1B.w) * inv;
            out4[g1 * 8 + q] = r;
        }
    }
}

// ============ fallback: round-8 5-kernel pipeline ============

__global__ void __launch_bounds__(512)
hist_kernel_na(const int* __restrict__ dst, int* __restrict__ H,
               int n_edges, int nbuckets) {
    __shared__ int lh[MAXB];
    for (int j = threadIdx.x; j < nbuckets; j += 512) lh[j] = 0;
    __syncthreads();
    int c0 = blockIdx.x * PCHUNK;
    int c1 = min(c0 + PCHUNK, n_edges);
#pragma unroll
    for (int g = 0; g < 4; ++g) {
        int i = c0 + g * 2048 + threadIdx.x * 4;
        if (i + 3 < c1) {
            int4 d = *(const int4*)(dst + i);
            atomicAdd(&lh[d.x >> NPB_SHIFT], 1);
            atomicAdd(&lh[d.y >> NPB_SHIFT], 1);
            atomicAdd(&lh[d.z >> NPB_SHIFT], 1);
            atomicAdd(&lh[d.w >> NPB_SHIFT], 1);
        } else {
            for (int k = i; k < c1; ++k)
                atomicAdd(&lh[dst[k] >> NPB_SHIFT], 1);
        }
    }
    __syncthreads();
    int* row = H + (size_t)blockIdx.x * nbuckets;
    for (int j = threadIdx.x; j < nbuckets; j += 512) row[j] = lh[j];
}

__global__ void __launch_bounds__(MAXBLK)
colscan_kernel(int* __restrict__ H, int* __restrict__ colsum,
               int nblocks, int nbuckets) {
    __shared__ int shm[MAXBLK];
    int j = blockIdx.x;
    int t = threadIdx.x;
    int v = (t < nblocks) ? H[(size_t)t * nbuckets + j] : 0;
    shm[t] = v;
    __syncthreads();
    for (int off = 1; off < MAXBLK; off <<= 1) {
        int u = (t >= off) ? shm[t - off] : 0;
        __syncthreads();
        shm[t] += u;
        __syncthreads();
    }
    if (t < nblocks) H[(size_t)t * nbuckets + j] = shm[t] - v;
    if (t == nblocks - 1) colsum[j] = shm[t];
}

__global__ void __launch_bounds__(MAXB)
exscan_kernel(const int* __restrict__ in, int* __restrict__ out, int n) {
    __shared__ int shm[MAXB];
    int t = threadIdx.x;
    int v = (t < n) ? in[t] : 0;
    shm[t] = v;
    __syncthreads();
    for (int off = 1; off < MAXB; off <<= 1) {
        int u = (t >= off) ? shm[t - off] : 0;
        __syncthreads();
        shm[t] += u;
        __syncthreads();
    }
    if (t < n) out[t] = shm[t] - v;
}

__global__ void __launch_bounds__(512)
partition_kernel_na(const int* __restrict__ src, const int* __restrict__ dst,
                    const int* __restrict__ H, const int* __restrict__ goff,
                    int* __restrict__ packed, int n_edges, int nbuckets) {
    __shared__ int lbase[MAXB];
    __shared__ int lrank[MAXB];
    const int* row = H + (size_t)blockIdx.x * nbuckets;
    for (int j = threadIdx.x; j < nbuckets; j += 512) {
        lbase[j] = goff[j] + row[j];
        lrank[j] = 0;
    }
    __syncthreads();
    int c0 = blockIdx.x * PCHUNK;
    int c1 = min(c0 + PCHUNK, n_edges);
#pragma unroll
    for (int g = 0; g < 4; ++g) {
        int i = c0 + g * 2048 + threadIdx.x * 4;
        if (i + 3 < c1) {
            int4 d = *(const int4*)(dst + i);
            int4 s = *(const int4*)(src + i);
            int b0 = d.x >> NPB_SHIFT, b1 = d.y >> NPB_SHIFT;
            int b2 = d.z >> NPB_SHIFT, b3 = d.w >> NPB_SHIFT;
            int r0 = atomicAdd(&lrank[b0], 1);
            int r1 = atomicAdd(&lrank[b1], 1);
            int r2 = atomicAdd(&lrank[b2], 1);
            int r3 = atomicAdd(&lrank[b3], 1);
            packed[lbase[b0] + r0] = (s.x << NPB_SHIFT) | (d.x & NPB_MASK);
            packed[lbase[b1] + r1] = (s.y << NPB_SHIFT) | (d.y & NPB_MASK);
            packed[lbase[b2] + r2] = (s.z << NPB_SHIFT) | (d.z & NPB_MASK);
            packed[lbase[b3] + r3] = (s.w << NPB_SHIFT) | (d.w & NPB_MASK);
        } else {
            for (int k = i; k < c1; ++k) {
                int d = dst[k];
                int b = d >> NPB_SHIFT;
                int r = atomicAdd(&lrank[b], 1);
                packed[lbase[b] + r] = (src[k] << NPB_SHIFT) | (d & NPB_MASK);
            }
        }
    }
}

__global__ void __launch_bounds__(512)
sort_aggregate_kernel(const float4* __restrict__ x4,
                      const int* __restrict__ goff,
                      const int* __restrict__ packed,
                      float4* __restrict__ out4,
                      int n_nodes, int n_edges, int nbuckets) {
    __shared__ int shist[NPB];
    __shared__ int soff[NPB];
    __shared__ int scur[NPB];
    __shared__ int sorted[CAP];
    int b = blockIdx.x;
    int n0 = b << NPB_SHIFT;
    int t = threadIdx.x;
    int seg_start = goff[b];
    int seg_end   = (b + 1 < nbuckets) ? goff[b + 1] : n_edges;
    int node = t >> 3;
    int q    = t & 7;
    float4 a0A = {0,0,0,0}, a0B = {0,0,0,0};
    float4 a1A = {0,0,0,0}, a1B = {0,0,0,0};
    int deg0 = 0, deg1 = 0;
    for (int pos = seg_start; pos < seg_end; pos += CAP) {
        int ch = min(CAP, seg_end - pos);
        for (int i = t; i < NPB; i += 512) shist[i] = 0;
        __syncthreads();
        int cc[8];
#pragma unroll
        for (int j = 0; j < 8; ++j) {
            int i = t + j * 512;
            if (i < ch) {
                int p = packed[pos + i];
                cc[j] = p;
                atomicAdd(&shist[p & NPB_MASK], 1);
            }
        }
        __syncthreads();
        if (t < 64) {
            int a  = shist[2 * t];
            int b2 = shist[2 * t + 1];
            int v = a + b2;
            for (int off = 1; off < 64; off <<= 1) {
                int u = __shfl_up(v, off, 64);
                if (t >= off) v += u;
            }
            int excl = v - (a + b2);
            soff[2 * t]     = excl;  soff[2 * t + 1] = excl + a;
            scur[2 * t]     = excl;  scur[2 * t + 1] = excl + a;
        }
        __syncthreads();
#pragma unroll
        for (int j = 0; j < 8; ++j) {
            int i = t + j * 512;
            if (i < ch) {
                int p = cc[j];
                int r = atomicAdd(&scur[p & NPB_MASK], 1);
                sorted[r] = p >> NPB_SHIFT;
            }
        }
        __syncthreads();
        {
            int cnt0 = shist[node];
            accum_node(x4, sorted, soff[node], cnt0, q, a0A, a0B);
            deg0 += cnt0;
            int cnt1 = shist[node + 64];
            accum_node(x4, sorted, soff[node + 64], cnt1, q, a1A, a1B);
            deg1 += cnt1;
        }
        __syncthreads();
    }
    int g0 = n0 + node;
    if (g0 < n_nodes) {
        float inv = 1.0f / (float)max(deg0, 1);
        float4 r;
        r.x = (a0A.x + a0B.x) * inv; r.y = (a0A.y + a0B.y) * inv;
        r.z = (a0A.z + a0B.z) * inv; r.w = (a0A.w + a0B.w) * inv;
        out4[g0 * 8 + q] = r;
    }
    int g1 = n0 + 64 + node;
    if (g1 < n_nodes) {
        float inv = 1.0f / (float)max(deg1, 1);
        float4 r;
        r.x = (a1A.x + a1B.x) * inv; r.y = (a1A.y + a1B.y) * inv;
        r.z = (a1A.z + a1B.z) * inv; r.w = (a1A.w + a1B.w) * inv;
        out4[g1 * 8 + q] = r;
    }
}

// ============ last-resort: atomic push path ============

__global__ void zero_f32_kernel(float* __restrict__ out, float* __restrict__ deg,
                                int n_out, int n_nodes) {
    int stride = gridDim.x * blockDim.x;
    for (int t = blockIdx.x * blockDim.x + threadIdx.x; t < n_out; t += stride)
        out[t] = 0.0f;
    for (int t = blockIdx.x * blockDim.x + threadIdx.x; t < n_nodes; t += stride)
        deg[t] = 0.0f;
}

__global__ void scatter_kernel(const float* __restrict__ x,
                               const int* __restrict__ src,
                               const int* __restrict__ dst,
                               float* __restrict__ out,
                               float* __restrict__ deg, int n_edges) {
    long long t = (long long)blockIdx.x * blockDim.x + threadIdx.x;
    long long total = (long long)n_edges * DIM;
    if (t >= total) return;
    int e = (int)(t >> 5);
    int f = (int)(t & 31);
    atomicAdd(&out[(long long)dst[e] * DIM + f], x[(long long)src[e] * DIM + f]);
    if (f == 0) atomicAdd(&deg[dst[e]], 1.0f);
}

__global__ void div_kernel(float* __restrict__ out, const float* __restrict__ deg,
                           int n_out) {
    int t = blockIdx.x * blockDim.x + threadIdx.x;
    if (t >= n_out) return;
    out[t] = out[t] / fmaxf(deg[t >> 5], 1.0f);
}

// ============ launch ============

extern "C" void kernel_launch(void* const* d_in, const int* in_sizes, int n_in,
                              void* d_out, int out_size, void* d_ws, size_t ws_size,
                              hipStream_t stream) {
    const float* x   = (const float*)d_in[0];
    const int*   src = (const int*)d_in[1];
    const int*   dst = (const int*)d_in[2];
    float* out = (float*)d_out;

    int n_nodes = in_sizes[0] / DIM;
    int n_edges = in_sizes[1];
    int n_out   = out_size;

    int nbuckets = (n_nodes + NPB - 1) >> NPB_SHIFT;
    bool pack_ok = (n_nodes < (1 << 24)) && (nbuckets <= MAXB);

    // ---- try cooperative fused path ----
    if (pack_ok) {
        int dev = 0;
        bool qok = (hipGetDevice(&dev) == hipSuccess);
        int coop = 0, ncu = 0, occ = 0;
        if (qok)
            qok = (hipDeviceGetAttribute(&coop, hipDeviceAttributeCooperativeLaunch,
                                         dev) == hipSuccess);
        if (qok)
            qok = (hipDeviceGetAttribute(&ncu,
                                         hipDeviceAttributeMultiprocessorCount,
                                         dev) == hipSuccess);
        if (qok)
            qok = (hipOccupancyMaxActiveBlocksPerMultiprocessor(
                       &occ, fused_kernel, 512, 0) == hipSuccess);
        if (qok && coop && ncu > 0 && occ > 0) {
            int G = nbuckets;
            if (G > occ * ncu) G = occ * ncu;
            if (G > 1024) G = 1024;
            int chunk = (((n_edges + G - 1) / G) + 3) & ~3;
            size_t need = ((size_t)G * nbuckets + 2 * nbuckets + n_edges)
                          * sizeof(int);
            if (chunk <= FIT * 2048 && ws_size >= need) {
                int* H      = (int*)d_ws;
                int* colsum = H + (size_t)G * nbuckets;
                int* goff   = colsum + nbuckets;
                int* packed = goff + nbuckets;

                const float4* x4p = (const float4*)x;
                float4* o4p = (float4*)out;
                void* kargs[] = {(void*)&x4p, (void*)&src, (void*)&dst,
                                 (void*)&H, (void*)&colsum, (void*)&goff,
                                 (void*)&packed, (void*)&o4p, (void*)&n_nodes,
                                 (void*)&n_edges, (void*)&nbuckets,
                                 (void*)&chunk};
                hipError_t err = hipLaunchCooperativeKernel(
                    (const void*)fused_kernel, dim3(G), dim3(512), kargs, 0,
                    stream);
                if (err == hipSuccess) return;
            }
        }
    }

    // ---- fallback: round-8 5-kernel pipeline ----
    {
        int nblocks = (n_edges + PCHUNK - 1) / PCHUNK;
        size_t need = ((size_t)nblocks * nbuckets + 2 * nbuckets + n_edges)
                      * sizeof(int);
        if (pack_ok && nblocks <= MAXBLK && ws_size >= need) {
            int* H      = (int*)d_ws;
            int* colsum = H + (size_t)nblocks * nbuckets;
            int* goff   = colsum + nbuckets;
            int* packed = goff + nbuckets;

            hist_kernel_na<<<nblocks, 512, 0, stream>>>(dst, H, n_edges, nbuckets);
            colscan_kernel<<<nbuckets, MAXBLK, 0, stream>>>(H, colsum, nblocks,
                                                            nbuckets);
            exscan_kernel<<<1, MAXB, 0, stream>>>(colsum, goff, nbuckets);
            partition_kernel_na<<<nblocks, 512, 0, stream>>>(src, dst, H, goff,
                                                             packed, n_edges,
                                                             nbuckets);
            sort_aggregate_kernel<<<nbuckets, 512, 0, stream>>>(
                (const float4*)x, goff, packed, (float4*)out, n_nodes, n_edges,
                nbuckets);
            return;
        }
    }

    // ---- last resort: atomic push ----
    {
        float* deg = (float*)d_ws;
        int threads = 256;
        int blocks  = (n_out + threads - 1) / threads;
        zero_f32_kernel<<<blocks, threads, 0, stream>>>(out, deg, n_out, n_nodes);
        long long total = (long long)n_edges * DIM;
        int sblocks = (int)((total + threads - 1) / threads);
        scatter_kernel<<<sblocks, threads, 0, stream>>>(x, src, dst, out, deg,
                                                        n_edges);
        div_kernel<<<blocks, threads, 0, stream>>>(out, deg, n_out);
    }
}

// Round 12
// 128.941 us; speedup vs baseline: 2.3192x; 2.3192x over previous
//
#include <hip/hip_runtime.h>

#define DIM 32
#define NPB 128            // nodes per bucket (shift 7); sort_aggregate assumes 128
#define NPB_SHIFT 7
#define NPB_MASK 127
#define MAXB 1024          // max buckets supported by the LDS hists / scan
#define PCHUNK 8192        // edges per hist/partition block (512 thr x 16 edges)
#define MAXBLK 256         // max partition blocks (colscan loads one column/block)
#define CAP 4096           // edges sorted per pass in LDS
#define TILE 8192          // legacy scan tile (fallback path)

// ================= bucketed sort-aggregate path (atomic-free partition) ======

__global__ void zero_i32_kernel(int* __restrict__ p, int n) {
    int t = blockIdx.x * blockDim.x + threadIdx.x;
    if (t < n) p[t] = 0;
}

// Per-chunk LDS histogram of bucket ids -> non-atomic coalesced row write
// into H[b][nbuckets]. No global atomics.
__global__ void __launch_bounds__(512)
hist_kernel_na(const int* __restrict__ dst, int* __restrict__ H,
               int n_edges, int nbuckets) {
    __shared__ int lh[MAXB];
    for (int j = threadIdx.x; j < nbuckets; j += 512) lh[j] = 0;
    __syncthreads();
    int c0 = blockIdx.x * PCHUNK;
    int c1 = min(c0 + PCHUNK, n_edges);
#pragma unroll
    for (int g = 0; g < 4; ++g) {
        int i = c0 + g * 2048 + threadIdx.x * 4;
        if (i + 3 < c1) {
            int4 d = *(const int4*)(dst + i);
            atomicAdd(&lh[d.x >> NPB_SHIFT], 1);
            atomicAdd(&lh[d.y >> NPB_SHIFT], 1);
            atomicAdd(&lh[d.z >> NPB_SHIFT], 1);
            atomicAdd(&lh[d.w >> NPB_SHIFT], 1);
        } else {
            for (int k = i; k < c1; ++k)
                atomicAdd(&lh[dst[k] >> NPB_SHIFT], 1);
        }
    }
    __syncthreads();
    int* row = H + (size_t)blockIdx.x * nbuckets;
    for (int j = threadIdx.x; j < nbuckets; j += 512) row[j] = lh[j];
}

// One block per bucket: exclusive scan down the bucket's column of H
// (in place), column total -> colsum[j]. nblocks <= MAXBLK.
__global__ void __launch_bounds__(MAXBLK)
colscan_kernel(int* __restrict__ H, int* __restrict__ colsum,
               int nblocks, int nbuckets) {
    __shared__ int sh[MAXBLK];
    int j = blockIdx.x;
    int t = threadIdx.x;
    int v = (t < nblocks) ? H[(size_t)t * nbuckets + j] : 0;
    sh[t] = v;
    __syncthreads();
    for (int off = 1; off < MAXBLK; off <<= 1) {
        int u = (t >= off) ? sh[t - off] : 0;
        __syncthreads();
        sh[t] += u;
        __syncthreads();
    }
    if (t < nblocks) H[(size_t)t * nbuckets + j] = sh[t] - v;  // exclusive
    if (t == nblocks - 1) colsum[j] = sh[t];                   // total
}

// Single-block exclusive scan of <=MAXB values: colsum -> goff.
__global__ void __launch_bounds__(MAXB)
exscan_kernel(const int* __restrict__ in, int* __restrict__ out, int n) {
    __shared__ int sh[MAXB];
    int t = threadIdx.x;
    int v = (t < n) ? in[t] : 0;
    sh[t] = v;
    __syncthreads();
    for (int off = 1; off < MAXB; off <<= 1) {
        int u = (t >= off) ? sh[t - off] : 0;
        __syncthreads();
        sh[t] += u;
        __syncthreads();
    }
    if (t < n) out[t] = sh[t] - v;
}

// Partition edges into bucket-contiguous packed array.
// Block base per bucket = goff[j] + H[b][j] (coalesced row read; NO atomics).
// packed = (src << NPB_SHIFT) | (dst & NPB_MASK)
__global__ void __launch_bounds__(512)
partition_kernel_na(const int* __restrict__ src, const int* __restrict__ dst,
                    const int* __restrict__ H, const int* __restrict__ goff,
                    int* __restrict__ packed, int n_edges, int nbuckets) {
    __shared__ int lbase[MAXB];
    __shared__ int lrank[MAXB];
    const int* row = H + (size_t)blockIdx.x * nbuckets;
    for (int j = threadIdx.x; j < nbuckets; j += 512) {
        lbase[j] = goff[j] + row[j];
        lrank[j] = 0;
    }
    __syncthreads();
    int c0 = blockIdx.x * PCHUNK;
    int c1 = min(c0 + PCHUNK, n_edges);
#pragma unroll
    for (int g = 0; g < 4; ++g) {
        int i = c0 + g * 2048 + threadIdx.x * 4;
        if (i + 3 < c1) {
            int4 d = *(const int4*)(dst + i);
            int4 s = *(const int4*)(src + i);
            int b0 = d.x >> NPB_SHIFT;
            int b1 = d.y >> NPB_SHIFT;
            int b2 = d.z >> NPB_SHIFT;
            int b3 = d.w >> NPB_SHIFT;
            int r0 = atomicAdd(&lrank[b0], 1);
            int r1 = atomicAdd(&lrank[b1], 1);
            int r2 = atomicAdd(&lrank[b2], 1);
            int r3 = atomicAdd(&lrank[b3], 1);
            packed[lbase[b0] + r0] = (s.x << NPB_SHIFT) | (d.x & NPB_MASK);
            packed[lbase[b1] + r1] = (s.y << NPB_SHIFT) | (d.y & NPB_MASK);
            packed[lbase[b2] + r2] = (s.z << NPB_SHIFT) | (d.z & NPB_MASK);
            packed[lbase[b3] + r3] = (s.w << NPB_SHIFT) | (d.w & NPB_MASK);
        } else {
            for (int k = i; k < c1; ++k) {
                int d = dst[k];
                int b = d >> NPB_SHIFT;
                int r = atomicAdd(&lrank[b], 1);
                packed[lbase[b] + r] = (src[k] << NPB_SHIFT) | (d & NPB_MASK);
            }
        }
    }
}

__device__ inline void f4add(float4& a, float4 v) {
    a.x += v.x; a.y += v.y; a.z += v.z; a.w += v.w;
}

// Sum x4 rows listed in LDS `sorted[s0 .. s0+cnt)` into two partial float4 accs.
__device__ inline void accum_node(const float4* __restrict__ x4,
                                  const int* sorted, int s0, int cnt, int q,
                                  float4& accA, float4& accB) {
    int k = 0;
    for (; k + 3 < cnt; k += 4) {
        int i0 = sorted[s0 + k];
        int i1 = sorted[s0 + k + 1];
        int i2 = sorted[s0 + k + 2];
        int i3 = sorted[s0 + k + 3];
        float4 v0 = x4[i0 * 8 + q];
        float4 v1 = x4[i1 * 8 + q];
        float4 v2 = x4[i2 * 8 + q];
        float4 v3 = x4[i3 * 8 + q];
        f4add(accA, v0); f4add(accB, v1); f4add(accA, v2); f4add(accB, v3);
    }
    for (; k < cnt; ++k) f4add(accA, x4[sorted[s0 + k] * 8 + q]);
}

// One 512-thread block per 128-node bucket: in-LDS counting sort of the
// bucket's edges by local dst, then atomic-free register accumulation.
__global__ void __launch_bounds__(512)
sort_aggregate_kernel(const float4* __restrict__ x4,
                      const int* __restrict__ goff,
                      const int* __restrict__ packed,
                      float4* __restrict__ out4,
                      int n_nodes, int n_edges, int nbuckets) {
    __shared__ int shist[NPB];
    __shared__ int soff[NPB];
    __shared__ int scur[NPB];
    __shared__ int sorted[CAP];

    int b = blockIdx.x;
    int n0 = b << NPB_SHIFT;
    int t = threadIdx.x;
    int seg_start = goff[b];
    int seg_end   = (b + 1 < nbuckets) ? goff[b + 1] : n_edges;

    int node = t >> 3;        // 0..63 (batch 0: node, batch 1: node+64)
    int q    = t & 7;         // feature quad
    float4 a0A = {0,0,0,0}, a0B = {0,0,0,0};
    float4 a1A = {0,0,0,0}, a1B = {0,0,0,0};
    int deg0 = 0, deg1 = 0;

    for (int pos = seg_start; pos < seg_end; pos += CAP) {
        int chunk = min(CAP, seg_end - pos);
        for (int i = t; i < NPB; i += 512) shist[i] = 0;
        __syncthreads();
        for (int i = t; i < chunk; i += 512)
            atomicAdd(&shist[packed[pos + i] & NPB_MASK], 1);
        __syncthreads();
        if (t < NPB) soff[t] = shist[t];
        __syncthreads();
        for (int off = 1; off < NPB; off <<= 1) {
            int v = (t < NPB && t >= off) ? soff[t - off] : 0;
            __syncthreads();
            if (t < NPB) soff[t] += v;
            __syncthreads();
        }
        if (t < NPB) {
            int e = soff[t] - shist[t];
            soff[t] = e;
            scur[t] = e;
        }
        __syncthreads();
        for (int i = t; i < chunk; i += 512) {
            int p = packed[pos + i];
            int r = atomicAdd(&scur[p & NPB_MASK], 1);
            sorted[r] = p >> NPB_SHIFT;
        }
        __syncthreads();
        {
            int c0 = shist[node];
            accum_node(x4, sorted, soff[node], c0, q, a0A, a0B);
            deg0 += c0;
            int c1 = shist[node + 64];
            accum_node(x4, sorted, soff[node + 64], c1, q, a1A, a1B);
            deg1 += c1;
        }
        __syncthreads();
    }

    int g0 = n0 + node;
    if (g0 < n_nodes) {
        float inv = 1.0f / (float)max(deg0, 1);
        float4 r;
        r.x = (a0A.x + a0B.x) * inv; r.y = (a0A.y + a0B.y) * inv;
        r.z = (a0A.z + a0B.z) * inv; r.w = (a0A.w + a0B.w) * inv;
        out4[g0 * 8 + q] = r;
    }
    int g1 = n0 + 64 + node;
    if (g1 < n_nodes) {
        float inv = 1.0f / (float)max(deg1, 1);
        float4 r;
        r.x = (a1A.x + a1B.x) * inv; r.y = (a1A.y + a1B.y) * inv;
        r.z = (a1A.z + a1B.z) * inv; r.w = (a1A.w + a1B.w) * inv;
        out4[g1 * 8 + q] = r;
    }
}

// ================= fallback: sorted (pull) path =================

__global__ void hist_kernel(const int* __restrict__ dst, int* __restrict__ counts,
                            int n_edges) {
    int t = blockIdx.x * blockDim.x + threadIdx.x;
    if (t < n_edges) atomicAdd(&counts[dst[t]], 1);
}

__global__ void scan_part1(const int* __restrict__ counts,
                           int* __restrict__ block_sums, int n) {
    __shared__ int sh[256];
    int base = blockIdx.x * TILE + threadIdx.x * 32;
    int s = 0;
#pragma unroll
    for (int i = 0; i < 32; ++i) {
        int idx = base + i;
        if (idx < n) s += counts[idx];
    }
    sh[threadIdx.x] = s;
    __syncthreads();
    for (int off = 128; off > 0; off >>= 1) {
        if (threadIdx.x < off) sh[threadIdx.x] += sh[threadIdx.x + off];
        __syncthreads();
    }
    if (threadIdx.x == 0) block_sums[blockIdx.x] = sh[0];
}

__global__ void scan_part2(int* __restrict__ block_sums, int nb) {
    if (blockIdx.x == 0 && threadIdx.x == 0) {
        int run = 0;
        for (int i = 0; i < nb; ++i) {
            int v = block_sums[i];
            block_sums[i] = run;
            run += v;
        }
    }
}

__global__ void scan_part3(const int* __restrict__ counts,
                           const int* __restrict__ block_sums,
                           int* __restrict__ offsets, int n) {
    __shared__ int sh[256];
    int tid = threadIdx.x;
    int base = blockIdx.x * TILE + tid * 32;
    int local[32];
    int s = 0;
#pragma unroll
    for (int i = 0; i < 32; ++i) {
        int idx = base + i;
        int v = (idx < n) ? counts[idx] : 0;
        local[i] = v;
        s += v;
    }
    sh[tid] = s;
    __syncthreads();
    for (int off = 1; off < 256; off <<= 1) {
        int v = (tid >= off) ? sh[tid - off] : 0;
        __syncthreads();
        sh[tid] += v;
        __syncthreads();
    }
    int run = block_sums[blockIdx.x] + ((tid == 0) ? 0 : sh[tid - 1]);
#pragma unroll
    for (int i = 0; i < 32; ++i) {
        int idx = base + i;
        if (idx < n) offsets[idx] = run;
        run += local[i];
    }
}

__global__ void scatter_sort_kernel(const int* __restrict__ src,
                                    const int* __restrict__ dst,
                                    int* __restrict__ cursors,
                                    int* __restrict__ sorted_src,
                                    int n_edges) {
    int t = blockIdx.x * blockDim.x + threadIdx.x;
    if (t < n_edges) {
        int pos = atomicAdd(&cursors[dst[t]], 1);
        sorted_src[pos] = src[t];
    }
}

__global__ void aggregate_kernel(const float* __restrict__ x,
                                 const int* __restrict__ seg_end,
                                 const int* __restrict__ sorted_src,
                                 float4* __restrict__ out,
                                 int n_nodes) {
    int t = blockIdx.x * blockDim.x + threadIdx.x;
    int n = t >> 3;
    if (n >= n_nodes) return;
    int q = t & 7;
    int end   = seg_end[n];
    int start = (n == 0) ? 0 : seg_end[n - 1];
    const float4* x4 = (const float4*)x;
    float4 acc0 = make_float4(0.f, 0.f, 0.f, 0.f);
    float4 acc1 = make_float4(0.f, 0.f, 0.f, 0.f);
    int k = start;
    for (; k + 1 < end; k += 2) {
        int s0 = sorted_src[k];
        int s1 = sorted_src[k + 1];
        f4add(acc0, x4[s0 * 8 + q]);
        f4add(acc1, x4[s1 * 8 + q]);
    }
    if (k < end) f4add(acc0, x4[sorted_src[k] * 8 + q]);
    float inv = 1.0f / (float)max(end - start, 1);
    float4 r;
    r.x = (acc0.x + acc1.x) * inv;
    r.y = (acc0.y + acc1.y) * inv;
    r.z = (acc0.z + acc1.z) * inv;
    r.w = (acc0.w + acc1.w) * inv;
    out[n * 8 + q] = r;
}

// ================= launch =================

extern "C" void kernel_launch(void* const* d_in, const int* in_sizes, int n_in,
                              void* d_out, int out_size, void* d_ws, size_t ws_size,
                              hipStream_t stream) {
    const float* x   = (const float*)d_in[0];
    const int*   src = (const int*)d_in[1];
    const int*   dst = (const int*)d_in[2];
    float* out = (float*)d_out;

    int n_nodes = in_sizes[0] / DIM;
    int n_edges = in_sizes[1];
    int n_out   = out_size;

    int nbuckets = (n_nodes + NPB - 1) >> NPB_SHIFT;
    int nblocks  = (n_edges + PCHUNK - 1) / PCHUNK;
    size_t need_new = ((size_t)nblocks * nbuckets + 2 * nbuckets + n_edges)
                      * sizeof(int);
    bool pack_ok = (n_nodes < (1 << 24)) && (nbuckets <= MAXB) &&
                   (nblocks <= MAXBLK);

    if (pack_ok && ws_size >= need_new) {
        int* H      = (int*)d_ws;                       // [nblocks][nbuckets]
        int* colsum = H + (size_t)nblocks * nbuckets;   // [nbuckets]
        int* goff   = colsum + nbuckets;                // [nbuckets] (preserved)
        int* packed = goff + nbuckets;                  // [n_edges]

        hist_kernel_na<<<nblocks, 512, 0, stream>>>(dst, H, n_edges, nbuckets);
        colscan_kernel<<<nbuckets, MAXBLK, 0, stream>>>(H, colsum, nblocks,
                                                        nbuckets);
        exscan_kernel<<<1, MAXB, 0, stream>>>(colsum, goff, nbuckets);
        partition_kernel_na<<<nblocks, 512, 0, stream>>>(src, dst, H, goff,
                                                         packed, n_edges,
                                                         nbuckets);
        sort_aggregate_kernel<<<nbuckets, 512, 0, stream>>>((const float4*)x, goff,
                                                            packed, (float4*)out,
                                                            n_nodes, n_edges,
                                                            nbuckets);
    } else {
        // fallback: dst-sorted pull path (round-4 pipeline)
        int nb = (n_nodes + TILE - 1) / TILE;
        int* counts     = (int*)d_ws;
        int* offsets    = counts + n_nodes;
        int* sorted_src = offsets + n_nodes;
        int* block_sums = sorted_src + n_edges;

        zero_i32_kernel<<<(n_nodes + 255) / 256, 256, 0, stream>>>(counts, n_nodes);
        int eb = (n_edges + 255) / 256;
        hist_kernel<<<eb, 256, 0, stream>>>(dst, counts, n_edges);
        scan_part1<<<nb, 256, 0, stream>>>(counts, block_sums, n_nodes);
        scan_part2<<<1, 64, 0, stream>>>(block_sums, nb);
        scan_part3<<<nb, 256, 0, stream>>>(counts, block_sums, offsets, n_nodes);
        scatter_sort_kernel<<<eb, 256, 0, stream>>>(src, dst, offsets, sorted_src,
                                                    n_edges);
        int athreads = n_nodes * 8;
        int ab = (athreads + 255) / 256;
        aggregate_kernel<<<ab, 256, 0, stream>>>(x, offsets, sorted_src,
                                                 (float4*)out, n_nodes);
    }
}